// Round 3
// baseline (133.360 us; speedup 1.0000x reference)
//
#include <hip/hip_runtime.h>
#include <stdint.h>

#define NPRED 2048
#define MT    512
#define BLK   256
#define NCAND 512

template<int C>
__device__ __forceinline__ float dppminf(float v) {
  int o = __builtin_amdgcn_update_dpp(__float_as_int(v), __float_as_int(v), C, 0xF, 0xF, false);
  return fminf(v, __int_as_float(o));
}
template<int C>
__device__ __forceinline__ uint32_t dppminu(uint32_t v) {
  uint32_t o = (uint32_t)__builtin_amdgcn_update_dpp((int)v, (int)v, C, 0xF, 0xF, false);
  return v < o ? v : o;
}
__device__ __forceinline__ float wave_min_f32_l63(float v) {
  v = dppminf<0x111>(v); v = dppminf<0x112>(v); v = dppminf<0x114>(v);
  v = dppminf<0x118>(v); v = dppminf<0x142>(v); v = dppminf<0x143>(v);
  return __int_as_float(__builtin_amdgcn_readlane(__float_as_int(v), 63));
}
__device__ __forceinline__ uint32_t wave_min_u32_l63(uint32_t v) {
  v = dppminu<0x111>(v); v = dppminu<0x112>(v); v = dppminu<0x114>(v);
  v = dppminu<0x118>(v); v = dppminu<0x142>(v); v = dppminu<0x143>(v);
  return (uint32_t)__builtin_amdgcn_readlane((int)v, 63);
}

// Exact argmin over 512 targets (8/lane) with lowest-index tie-break.
__device__ __forceinline__ int argmin_pred(const float* txr, const float* tyr,
                                           uint32_t okm, float x, float y,
                                           uint32_t lane8) {
  const float INF = __builtin_inff();
  float d[8];
#pragma unroll
  for (int j = 0; j < 8; ++j) {
    float dx = __fsub_rn(txr[j], x);
    float dy = __fsub_rn(tyr[j], y);
    float d2 = __fadd_rn(__fmul_rn(dx, dx), __fmul_rn(dy, dy));
    d[j] = ((okm >> j) & 1u) ? d2 : INF;
  }
  float l1 = fminf(d[0], d[1]), l2 = fminf(d[2], d[3]);
  float l3 = fminf(d[4], d[5]), l4 = fminf(d[6], d[7]);
  float lmin = fminf(fminf(l1, l2), fminf(l3, l4));
  float g = wave_min_f32_l63(lmin);
  int jb = 7;
#pragma unroll
  for (int j = 6; j >= 0; --j) jb = (d[j] == g) ? j : jb;
  uint32_t cnd = (lmin == g) ? (lane8 | (uint32_t)jb) : 0x7FFFFFFFu;
  return (int)wave_min_u32_l63(cnd);
}

__global__ __launch_bounds__(BLK) void loss_kernel(const float* __restrict__ preds,
                                                   const float* __restrict__ targets,
                                                   double* __restrict__ acc) {
  const int b = blockIdx.x;
  const float* __restrict__ P = preds   + (size_t)b * NPRED * 5;
  const float* __restrict__ T = targets + (size_t)b * MT * 5;

  __shared__ uint64_t keys[NPRED];                     // 16 KB
  __shared__ uint64_t cand[NCAND];                     // 4 KB
  __shared__ float tgx[MT], tgy[MT], tga[MT], tgb[MT]; // 8 KB
  __shared__ float spx[MT], spy[MT], spa[MT], spb[MT]; // 8 KB
  __shared__ int hist[256];                            // 1 KB
  __shared__ uint32_t pairs[NCAND];                    // 2 KB
  __shared__ uint32_t validw[16];
  __shared__ uint64_t s_thrkey;
  __shared__ int s_npos, s_ntargs, s_first, s_B, s_ncand;
  __shared__ double red[5][BLK];                       // 10 KB

  const int tid = threadIdx.x;

  if (tid == 0) { s_npos = 0; s_ntargs = 0; s_first = 0; s_B = 0; s_ncand = 0; s_thrkey = 0ull; }
  hist[tid] = 0;
  if (tid < 16) validw[tid] = 0;
  __syncthreads();

  // ---- keys + histogram of conf in [0.5,1) + n_pos ----
  int cpos = 0;
  for (int i = tid; i < NPRED; i += BLK) {
    float c = P[i * 5 + 0];
    cpos += (c > 0.5f) ? 1 : 0;
    uint32_t cb = __float_as_uint(c);
    keys[i] = ((uint64_t)(~cb) << 32) | (uint32_t)i;   // asc key == conf desc, idx asc
    if (cb >= 0x3F000000u && cb < 0x3F800000u)
      atomicAdd(&hist[(cb >> 15) & 0xFF], 1);
  }
  atomicAdd(&s_npos, cpos);

  // ---- stage targets + validity + n_targs ----
  int ct = 0;
  for (int m = tid; m < MT; m += BLK) {
    float tp = T[m * 5 + 0];
    if (tp == 1.0f) { ct++; atomicOr(&validw[m >> 5], 1u << (m & 31)); }
    tgx[m] = T[m * 5 + 1];
    tgy[m] = T[m * 5 + 2];
    tga[m] = T[m * 5 + 3];
    tgb[m] = T[m * 5 + 4];
  }
  atomicAdd(&s_ntargs, ct);
  __syncthreads();
  const int n_pos = s_npos;
  const int n_targs = s_ntargs;

  // ---- wave0: suffix-scan histogram -> cutoff bucket B ----
  if (tid < 64) {
    const int lane = tid;
    int4 h4 = *reinterpret_cast<const int4*>(&hist[lane * 4]);
    int t = h4.x + h4.y + h4.z + h4.w;
    int S = t;
#pragma unroll
    for (int off = 1; off < 64; off <<= 1) {
      int o = __shfl_down(S, off);
      if (lane + off < 64) S += o;
    }
    int Snext = S - t;
    int s3 = h4.w + Snext;
    int s2 = h4.z + s3;
    int s1 = h4.y + s2;
    int s0 = h4.x + s1;
    int localB = -1;
    if      (s3 >= n_targs) localB = lane * 4 + 3;
    else if (s2 >= n_targs) localB = lane * 4 + 2;
    else if (s1 >= n_targs) localB = lane * 4 + 1;
    else if (s0 >= n_targs) localB = lane * 4 + 0;
    uint64_t q = __ballot(localB >= 0);
    if (q) {
      int hl = 63 - __clzll((long long)q);
      int B = __builtin_amdgcn_readlane(localB, hl);
      if (lane == 0) s_B = B;
    }
  }
  __syncthreads();
  const int B = s_B;

  // ---- gather candidates (bucket >= B) ----
  for (int i = tid; i < NPRED; i += BLK) {
    uint64_t k = keys[i];
    uint32_t cb = ~(uint32_t)(k >> 32);
    if (cb >= 0x3F000000u && cb < 0x3F800000u && (int)((cb >> 15) & 0xFF) >= B) {
      int slot = atomicAdd(&s_ncand, 1);
      if (slot < NCAND) cand[slot] = k;
    }
  }
  // zero-init sp so out-of-range speculative reads are benign
  for (int i = tid; i < NCAND; i += BLK) { spx[i] = 0.f; spy[i] = 0.f; spa[i] = 0.f; spb[i] = 0.f; }
  __syncthreads();
  const int ncand = min(s_ncand, NCAND);

  // ---- rank-sort: each thread ranks up to 2 candidates, scatters by rank ----
  {
    uint64_t ka = (tid < ncand) ? cand[tid] : ~0ull;
    uint64_t kb = (tid + BLK < ncand) ? cand[tid + BLK] : ~0ull;
    int ra = 0, rb = 0;
    for (int j = 0; j < ncand; ++j) {
      uint64_t kj = cand[j];
      ra += (kj < ka) ? 1 : 0;
      rb += (kj < kb) ? 1 : 0;
    }
    if (tid < ncand && ra < n_targs) {
      int idx = (int)(ka & 0xFFFFFFFFu);
      spx[ra] = P[idx * 5 + 1]; spy[ra] = P[idx * 5 + 2];
      spa[ra] = P[idx * 5 + 3]; spb[ra] = P[idx * 5 + 4];
    }
    if (tid < ncand && ra == n_targs - 1) s_thrkey = ka;
    if (tid + BLK < ncand && rb < n_targs) {
      int idx = (int)(kb & 0xFFFFFFFFu);
      spx[rb] = P[idx * 5 + 1]; spy[rb] = P[idx * 5 + 2];
      spa[rb] = P[idx * 5 + 3]; spb[rb] = P[idx * 5 + 4];
    }
    if (tid + BLK < ncand && rb == n_targs - 1) s_thrkey = kb;
  }
  __syncthreads();
  const uint64_t thrkey = s_thrkey;
  const int K = min(n_pos, n_targs);

  float maccx = 0.f, maccy = 0.f, macca = 0.f, maccb = 0.f;
  float accp = 0.f;

  if (tid < 64) {
    // ---- wave0: k=2 lookahead greedy match ----
    const int lane = tid;
    const uint32_t lane8 = (uint32_t)(lane << 3);
    float txr[8], tyr[8];
    uint32_t okm = (validw[lane >> 2] >> ((lane & 3) * 8)) & 0xFFu;
#pragma unroll
    for (int j = 0; j < 8; ++j) { txr[j] = tgx[lane * 8 + j]; tyr[j] = tgy[lane * 8 + j]; }

    int i = 0;
    float xa = spx[0], ya = spy[0], xb = spx[1], yb = spy[1];
    while (i < K) {
      int ip2 = min(i + 2, NCAND - 1), ip3 = min(i + 3, NCAND - 1);
      float x2 = spx[ip2], y2 = spy[ip2], x3 = spx[ip3], y3 = spy[ip3];

      int m0 = argmin_pred(txr, tyr, okm, xa, ya, lane8);
      int m1 = argmin_pred(txr, tyr, okm, xb, yb, lane8);

      okm &= ~(((m0 >> 3) == lane) ? (1u << (m0 & 7)) : 0u);
      if (lane == 0) pairs[i] = (uint32_t)m0;

      bool two = ((i + 1) < K) && (m1 != m0);
      if (two) {
        okm &= ~(((m1 >> 3) == lane) ? (1u << (m1 & 7)) : 0u);
        if (lane == 0) pairs[i + 1] = (uint32_t)m1;
        xa = x2; ya = y2; xb = x3; yb = y3;
        i += 2;
      } else {
        xa = xb; ya = yb; xb = x2; yb = y2;
        i += 1;
      }
    }
    // first valid unused target
    uint32_t fi = okm ? (uint32_t)(lane * 8 + __ffs(okm) - 1) : 0xFFFFFFFFu;
    fi = wave_min_u32_l63(fi);
    if (lane == 0) s_first = (fi < MT) ? (int)fi : 0;
  } else {
    // ---- waves 1-3: prob loss (t = key <= thrkey) ----
    for (int i = tid - 64; i < NPRED; i += (BLK - 64)) {
      uint64_t k = keys[i];
      float p = __uint_as_float(~(uint32_t)(k >> 32));
      bool tpos = (k <= thrkey);
      accp += tpos ? -fmaxf(logf(p), -100.0f)
                   : -fmaxf(log1pf(-p), -100.0f);
    }
  }
  __syncthreads();

  // ---- deferred MSE over matched pairs (all 256 threads) ----
  for (int r = tid; r < K; r += BLK) {
    int m = (int)pairs[r];
    float dx = __fsub_rn(spx[r], tgx[m]);
    float dy = __fsub_rn(spy[r], tgy[m]);
    float da = __fsub_rn(spa[r], tga[m]);
    float db = __fsub_rn(spb[r], tgb[m]);
    maccx += __fmul_rn(dx, dx);
    maccy += __fmul_rn(dy, dy);
    macca += __fmul_rn(da, da);
    maccb += __fmul_rn(db, db);
  }

  // ---- case_first window [n_pos, n_targs) ----
  if (n_pos < n_targs) {
    int f = s_first;
    float fx = tgx[f], fy = tgy[f], fa = tga[f], fb = tgb[f];
    for (int i = n_pos + tid; i < n_targs; i += BLK) {
      float dx = __fsub_rn(spx[i], fx);
      float dy = __fsub_rn(spy[i], fy);
      float da = __fsub_rn(spa[i], fa);
      float db = __fsub_rn(spb[i], fb);
      maccx += __fmul_rn(dx, dx);
      maccy += __fmul_rn(dy, dy);
      macca += __fmul_rn(da, da);
      maccb += __fmul_rn(db, db);
    }
  }

  // ---- block reduce (doubles) + global atomic ----
  red[0][tid] = (double)maccx;
  red[1][tid] = (double)maccy;
  red[2][tid] = (double)macca;
  red[3][tid] = (double)maccb;
  red[4][tid] = (double)accp;
  __syncthreads();
  for (int s = BLK / 2; s > 0; s >>= 1) {
    if (tid < s) {
#pragma unroll
      for (int c = 0; c < 5; ++c) red[c][tid] += red[c][tid + s];
    }
    __syncthreads();
  }
  if (tid == 0) {
#pragma unroll
    for (int c = 0; c < 5; ++c) atomicAdd(&acc[c], red[c][0]);
  }
}

__global__ void finalize_kernel(const double* __restrict__ acc,
                                float* __restrict__ out, double inv) {
  int c = threadIdx.x;
  if (c < 5) out[c] = (float)(acc[c] * inv);
}

extern "C" void kernel_launch(void* const* d_in, const int* in_sizes, int n_in,
                              void* d_out, int out_size, void* d_ws, size_t ws_size,
                              hipStream_t stream) {
  const float* preds = (const float*)d_in[0];
  const float* targets = (const float*)d_in[1];
  int B = in_sizes[0] / (NPRED * 5);

  double* acc = (double*)d_ws;
  hipMemsetAsync(acc, 0, 5 * sizeof(double), stream);
  loss_kernel<<<B, BLK, 0, stream>>>(preds, targets, acc);
  finalize_kernel<<<1, 64, 0, stream>>>(acc, (float*)d_out,
                                        1.0 / ((double)B * NPRED));
}